// Round 9
// baseline (482.346 us; speedup 1.0000x reference)
//
#include <hip/hip_runtime.h>

// B=4, C=512, H=W=64 -> N=4096 tokens, KEY_DIM=VALUE_DIM=512.
// Pipeline (all matmuls on v_mfma_f32_16x16x32_bf16, fp32 accum):
//   K0 conv_bf16  : f32->bf16 AND x transpose: Xb[b][n][c] token-major (LDS
//                   tile bounce).  Wb[m][d][c].  Overlays Pt (dead until K2).
//   K1 qkv_proj   : bf16 GEMM; x staging now ONE bf16x8 load/thread/stage
//                   (was 8 scalar 2B strided loads -- the last unvectorized
//                   path, Common-mistake #2).  Xt content byte-identical.
//   K2 attn_lsum_p: R4/R6 form (256 thr, 2x32KB DMA stages), 92 us.
//   K3 attn_pv    : O = V.Pexp^T + colsum partials.  R9: colsum moved OUT of
//                   the unrolled MFMA i-loop into a post-loop phase (re-read
//                   from Plds, same values/order -> bit-identical).  R8's inner
//                   `own` branch split the scheduling region 4x/stage and cost
//                   ~13 us vs R4's branch-free loop.
//   K4 colsum_reduce: scores[b][i] = sum_q0b scpart (4MB, tiny).
// Lessons: R5 direct global K-frag loads = 300us (latency death); R1/R2
// atomics cost 31MB RMW + 90MB read-alloc; R7 small blocks doubled barriers.
// No max-subtraction in softmax: logits ~ N(0,1), exp() can't overflow.
// ws: Qt/Kf/Vt 50.3 MB + l 64 KB + Pexp 134.2 MB (Xb/Wb overlaid) + scpart 4MB.

typedef short bf16x8 __attribute__((ext_vector_type(8)));
typedef float f32x4 __attribute__((ext_vector_type(4)));

#define NTOK 4096
#define DDIM 512
#define NB   4

__device__ __forceinline__ unsigned short f32_bf16(float f) {
  union { float f; unsigned u; } v; v.f = f;
  unsigned r = v.u + 0x7FFFu + ((v.u >> 16) & 1u);  // RNE
  return (unsigned short)(r >> 16);
}

__device__ __forceinline__ float bf16_f32(short s) {
  union { unsigned u; float f; } v;
  v.u = ((unsigned)(unsigned short)s) << 16;
  return v.f;
}

// Async global->LDS DMA, 16B per lane.
__device__ __forceinline__ void gload_lds16(const unsigned short* g,
                                            unsigned short* l) {
  __builtin_amdgcn_global_load_lds(
      (__attribute__((address_space(1))) void*)(g),
      (__attribute__((address_space(3))) void*)(l), 16, 0, 0);
}

// ---------------------------------------------------------------------------
// K0: f32->bf16 + x transpose.  Blocks [0,2048): x [b][c][n] -> Xb [b][n][c]
// via 64x64 LDS tile.  Blocks [2048,2432): Wq/Wk/Wv -> Wb[m][d][c] flat.
// ---------------------------------------------------------------------------
__global__ __launch_bounds__(256, 4) void conv_bf16(
    const float* __restrict__ x,
    const float* __restrict__ Wq,
    const float* __restrict__ Wk,
    const float* __restrict__ Wv,
    unsigned short* __restrict__ Xb,
    unsigned short* __restrict__ Wb)
{
  const int bid = blockIdx.x;
  const int tid = threadIdx.x;
  if (bid < 2048) {
    // x transpose tile: batch b, c-tile ct (8), n-tile nt (64)
    const int b  = bid >> 9;
    const int t  = bid & 511;
    const int c0 = (t >> 6) * 64;
    const int n0 = (t & 63) * 64;
    __shared__ __align__(16) unsigned short T[64][72];  // [n][c]
    const int cr = tid >> 2;        // c row 0..63
    const int cg = tid & 3;         // n group of 16
    const float* src = x + ((size_t)b * DDIM + c0 + cr) * NTOK + n0 + cg * 16;
    float v[16];
#pragma unroll
    for (int e4 = 0; e4 < 4; ++e4) {
      const float4 a = *(const float4*)(src + e4 * 4);
      v[e4 * 4 + 0] = a.x; v[e4 * 4 + 1] = a.y;
      v[e4 * 4 + 2] = a.z; v[e4 * 4 + 3] = a.w;
    }
#pragma unroll
    for (int e = 0; e < 16; ++e) T[cg * 16 + e][cr] = f32_bf16(v[e]);
    __syncthreads();
    const int nr  = tid >> 2;       // n row 0..63
    const int cg2 = tid & 3;        // c group of 16
    unsigned short* dst =
        Xb + ((size_t)b * NTOK + n0 + nr) * DDIM + c0 + cg2 * 16;
    *(bf16x8*)(dst)     = *(const bf16x8*)(&T[nr][cg2 * 16]);
    *(bf16x8*)(dst + 8) = *(const bf16x8*)(&T[nr][cg2 * 16 + 8]);
  } else {
    const int widx = bid - 2048;                 // [0,384)
    const int m    = widx >> 7;                  // 0..2
    const float* wsrc[3] = {Wq, Wk, Wv};
    const float* src = wsrc[m] + (size_t)(widx & 127) * 2048;
    unsigned short* dst = Wb + (size_t)m * 262144 + (size_t)(widx & 127) * 2048;
    const size_t i = (size_t)tid * 8;
    const float4 a = *(const float4*)(src + i);
    const float4 c = *(const float4*)(src + i + 4);
    bf16x8 tv;
    tv[0] = (short)f32_bf16(a.x); tv[1] = (short)f32_bf16(a.y);
    tv[2] = (short)f32_bf16(a.z); tv[3] = (short)f32_bf16(a.w);
    tv[4] = (short)f32_bf16(c.x); tv[5] = (short)f32_bf16(c.y);
    tv[6] = (short)f32_bf16(c.z); tv[7] = (short)f32_bf16(c.w);
    *(bf16x8*)(dst + i) = tv;
  }
}

// ---------------------------------------------------------------------------
// K1: QKV projection (bf16, token-major x).  Q[n,d] = sum_c x[n,c] * Wq[d,c].
// Staging: x and weights each ONE bf16x8 vector load/thread/stage.
// MFMA loop + epilogue identical to original (bit-identical results).
// ---------------------------------------------------------------------------
__global__ __launch_bounds__(256, 4) void qkv_proj(
    const unsigned short* __restrict__ Xb,   // [b][n][c] bf16 token-major
    const unsigned short* __restrict__ Wb,   // [m][d][c] bf16
    unsigned short* __restrict__ Qt,
    unsigned short* __restrict__ Kf,
    unsigned short* __restrict__ Vt)
{
  const int nt0 = blockIdx.x * 64;   // token tile
  const int d0  = blockIdx.y * 64;   // feature tile
  const int b   = blockIdx.z;
  const int tid = threadIdx.x;
  const int wave = tid >> 6;
  const int lane = tid & 63;
  const int l15  = lane & 15;
  const int quad = lane >> 4;

  __shared__ __align__(16) unsigned short Xt[64 * 40];     // [token][c]
  __shared__ __align__(16) unsigned short Wl[3][64 * 40];  // [q/k/v][d][c]

  f32x4 aq[4], ak[4], av[4];
#pragma unroll
  for (int i = 0; i < 4; ++i) {
    aq[i] = (f32x4){0.f,0.f,0.f,0.f};
    ak[i] = (f32x4){0.f,0.f,0.f,0.f};
    av[i] = (f32x4){0.f,0.f,0.f,0.f};
  }

  const unsigned short* xb = Xb + ((size_t)b * NTOK + nt0) * DDIM;
  const int tr  = tid >> 2;   // token row 0..63
  const int cgx = tid & 3;    // c group of 8
  const int wc8 = tid & 3;
  const int wdd = tid >> 2;

  for (int cc = 0; cc < DDIM; cc += 32) {
    __syncthreads();
    *(bf16x8*)(&Xt[tr * 40 + cgx * 8]) =
        *(const bf16x8*)(xb + (size_t)tr * DDIM + cc + cgx * 8);
#pragma unroll
    for (int m = 0; m < 3; ++m) {
      const bf16x8 t = *(const bf16x8*)(
          Wb + (size_t)m * 262144 + (size_t)(d0 + wdd) * 512 + cc + wc8 * 8);
      *(bf16x8*)(&Wl[m][wdd * 40 + wc8 * 8]) = t;
    }
    __syncthreads();

    bf16x8 xa  = *(const bf16x8*)(&Xt[(wave * 16 + l15) * 40 + quad * 8]);
    bf16x8 wva = *(const bf16x8*)(&Wl[2][(wave * 16 + l15) * 40 + quad * 8]);
#pragma unroll
    for (int nt = 0; nt < 4; ++nt) {
      bf16x8 wqf = *(const bf16x8*)(&Wl[0][(nt * 16 + l15) * 40 + quad * 8]);
      bf16x8 wkf = *(const bf16x8*)(&Wl[1][(nt * 16 + l15) * 40 + quad * 8]);
      bf16x8 xbf = *(const bf16x8*)(&Xt[(nt * 16 + l15) * 40 + quad * 8]);
      aq[nt] = __builtin_amdgcn_mfma_f32_16x16x32_bf16(xa,  wqf, aq[nt], 0, 0, 0);
      ak[nt] = __builtin_amdgcn_mfma_f32_16x16x32_bf16(xa,  wkf, ak[nt], 0, 0, 0);
      av[nt] = __builtin_amdgcn_mfma_f32_16x16x32_bf16(wva, xbf, av[nt], 0, 0, 0);
    }
  }

#pragma unroll
  for (int nt = 0; nt < 4; ++nt) {
#pragma unroll
    for (int r = 0; r < 4; ++r) {
      const int tokq = nt0 + wave * 16 + quad * 4 + r;
      const int dq   = d0 + nt * 16 + l15;
      Qt[((size_t)b * NTOK + tokq) * DDIM + dq] = f32_bf16(aq[nt][r]);
      // K fragment-tile store (B-operand of 16x16x32): key=tokq, d=dq
      {
        const int kblk  = (nt0 >> 4) + wave;
        const int dc    = (d0 >> 5) + (nt >> 1);
        const int laneK = ((nt & 1) * 2 + (l15 >> 3)) * 16 + quad * 4 + r;
        Kf[((size_t)(b * 256 + kblk) * 16 + dc) * 512 + laneK * 8 + (l15 & 7)] =
            f32_bf16(ak[nt][r]);
      }
      // V fragment-tile store: d = d0+wave*16+quad*4+r, i = nt0+nt*16+l15
      const int dblk  = (d0 >> 4) + wave;
      const int ic    = (nt0 >> 5) + (nt >> 1);
      const int laneV = ((nt & 1) * 2 + (l15 >> 3)) * 16 + quad * 4 + r;
      Vt[(size_t)b * DDIM * NTOK +
         ((size_t)(dblk * 128 + ic) * 64 + laneV) * 8 + (l15 & 7)] =
          f32_bf16(av[nt][r]);
    }
  }
}

// ---------------------------------------------------------------------------
#define SCALE 0.044194173824159216f  // 1/sqrt(512)

// ---------------------------------------------------------------------------
// K2: QK^T -> Pexp + row-sum atomics.  Grid (32 qb(128q), 4 kp(1024k), NB).
// Wave owns 32 q (qf[2][16] pinned, 128 VGPRs).  32-key stages via
// global_load_lds into Klds[2][32KB]; 2-phase dbuf.  (R4/R6 form, 92 us.)
// ---------------------------------------------------------------------------
__global__ __launch_bounds__(256, 2) void attn_lsum_p(
    const unsigned short* __restrict__ Qt,
    const unsigned short* __restrict__ Kf,
    unsigned short* __restrict__ Pt,
    float* __restrict__ lsum_g)
{
  const int qb = blockIdx.x;   // 128-q block
  const int kp = blockIdx.y;   // 1024-key part
  const int b  = blockIdx.z;
  const int tid  = threadIdx.x;
  const int wave = tid >> 6;
  const int lane = tid & 63;
  const int l15  = lane & 15;
  const int quad = lane >> 4;
  const int q0   = qb * 128 + wave * 32;  // wave's 32 q

  __shared__ __align__(16) unsigned short Klds[2][16384];  // 2 x 32KB

  // Q A-frags pinned: qf[qt][dc], 2x16x4 VGPRs = 128
  bf16x8 qf[2][16];
#pragma unroll
  for (int qt = 0; qt < 2; ++qt) {
    const unsigned short* qp =
        Qt + ((size_t)b * NTOK + q0 + qt * 16 + l15) * DDIM + quad * 8;
#pragma unroll
    for (int dc = 0; dc < 16; ++dc) qf[qt][dc] = *(const bf16x8*)(qp + dc * 32);
  }

  // P region: 64-q granularity
  unsigned short* Pq = Pt + (size_t)b * NTOK * NTOK +
                       (size_t)(qb * 2 + (wave >> 1)) * 262144;
  const int ntb = (wave & 1) * 2;  // nt base within region

  float ls[2][4] = {{0.f,0.f,0.f,0.f},{0.f,0.f,0.f,0.f}};

  // stage kc2 covers key-blocks kp*64 + kc2*2 .. +1 (32 keys, 32KB, flat)
  const unsigned short* Ksrc0 = Kf + ((size_t)(b * 256 + kp * 64) * 16) * 512;

#define KSTAGE(KC_, B_)                                                        \
  do {                                                                         \
    const unsigned short* ks_ = Ksrc0 + (size_t)(KC_)*16384;                   \
    _Pragma("unroll") for (int c_ = 0; c_ < 8; ++c_) {                         \
      const int ch_ = c_ * 4 + wave;                                           \
      gload_lds16(ks_ + ch_ * 512 + lane * 8, &Klds[B_][ch_ * 512]);           \
    }                                                                          \
  } while (0)

  KSTAGE(0, 0);
  __syncthreads();

  for (int kc2 = 0; kc2 < 32; ++kc2) {
    const int cb = kc2 & 1;
    if (kc2 < 31) KSTAGE(kc2 + 1, cb ^ 1);

#pragma unroll
    for (int kt = 0; kt < 2; ++kt) {
      const int kabs = kp * 64 + kc2 * 2 + kt;
      f32x4 s0 = (f32x4){0.f,0.f,0.f,0.f};
      f32x4 s1 = (f32x4){0.f,0.f,0.f,0.f};
#pragma unroll
      for (int dc = 0; dc < 16; ++dc) {
        const bf16x8 kbf =
            *(const bf16x8*)(&Klds[cb][(kt * 16 + dc) * 512 + lane * 8]);
        s0 = __builtin_amdgcn_mfma_f32_16x16x32_bf16(qf[0][dc], kbf, s0, 0, 0, 0);
        s1 = __builtin_amdgcn_mfma_f32_16x16x32_bf16(qf[1][dc], kbf, s1, 0, 0, 0);
      }
      // epilogue: key = kabs*16 + l15, q = q0 + qt*16 + quad*4 + r
      const int ic    = kabs >> 1;
      const int lt_hi = ((kabs & 1) * 2 + (l15 >> 3)) * 16;
      const int jj    = l15 & 7;
#pragma unroll
      for (int r = 0; r < 4; ++r) {
        const float e0 = __expf(s0[r] * SCALE);
        const float e1 = __expf(s1[r] * SCALE);
        ls[0][r] += e0;
        ls[1][r] += e1;
        Pq[((size_t)(ic * 4 + ntb) * 64 + lt_hi + quad * 4 + r) * 8 + jj] =
            f32_bf16(e0);
        Pq[((size_t)(ic * 4 + ntb + 1) * 64 + lt_hi + quad * 4 + r) * 8 + jj] =
            f32_bf16(e1);
      }
    }
    __syncthreads();
  }
#undef KSTAGE

  // reduce over the 16 key-columns (l15) and accumulate l_j
#pragma unroll
  for (int qt = 0; qt < 2; ++qt)
#pragma unroll
    for (int r = 0; r < 4; ++r) {
      float v = ls[qt][r];
      v += __shfl_xor(v, 1);
      v += __shfl_xor(v, 2);
      v += __shfl_xor(v, 4);
      v += __shfl_xor(v, 8);
      if (l15 == 0)
        unsafeAtomicAdd(&lsum_g[(size_t)b * NTOK + q0 + qt * 16 + quad * 4 + r], v);
    }
}

// ---------------------------------------------------------------------------
// K3: O = V.Pexp^T + colsum partials.  1D grid 1024, XCD-swizzled.
// 4 blk/CU x 4 waves = 16 waves/CU.  Wave owns 32 d x 64 q; o[2][4].
// MFMA i-loop is branch-free (R4 form); colsum runs as a SEPARATE post-loop
// phase on owned stages, re-reading Plds[cb] (still valid until the barrier).
// Same values, same fma order -> bit-identical.
// ---------------------------------------------------------------------------
__global__ __launch_bounds__(256, 4) void attn_pv(
    const unsigned short* __restrict__ Pt,
    const unsigned short* __restrict__ Vt,
    const float* __restrict__ lsum_g,
    float* __restrict__ out,
    float* __restrict__ scpart)
{
  const int g     = blockIdx.x;
  const int xcd   = g & 7;
  const int slot  = g >> 3;                    // [0,128)
  const int combo = (xcd << 1) | (slot >> 6);  // [0,16) = dpart + 4*b
  const int q0b   = slot & 63;
  const int dpart = combo & 3;                 // 0..3, 128 d each
  const int b     = combo >> 2;
  const int tid  = threadIdx.x;
  const int wave = tid >> 6;
  const int lane = tid & 63;
  const int l15  = lane & 15;
  const int quad = lane >> 4;

  const int dblk0 = dpart * 8 + wave * 2;  // base 16-d tile index (2/wave)
  const unsigned short* Pq =
      Pt + (size_t)b * NTOK * NTOK + (size_t)q0b * 262144;  // 128 ic x 2048
  const unsigned short* Vb =
      Vt + (size_t)b * DDIM * NTOK + lane * 8;
  float* scp = scpart + ((size_t)(b * 64 + q0b)) * NTOK;

  __shared__ __align__(16) unsigned short Plds[2][8192];  // 2 x 16KB (4 ic)

  float rlv[4];
#pragma unroll
  for (int nt = 0; nt < 4; ++nt)
    rlv[nt] = 1.0f / lsum_g[(size_t)b * NTOK + q0b * 64 + nt * 16 + l15];

  f32x4 o[2][4];
#pragma unroll
  for (int i = 0; i < 2; ++i)
#pragma unroll
    for (int j = 0; j < 4; ++j) o[i][j] = (f32x4){0.f,0.f,0.f,0.f};

  bf16x8 vA[2], vB[2];

#define LOADVN(D_, IC_)                                                        \
  do {                                                                         \
    _Pragma("unroll") for (int mt = 0; mt < 2; ++mt)                           \
      D_[mt] = *(const bf16x8*)(Vb + (size_t)(dblk0 + mt) * 65536 +            \
                                (size_t)(IC_)*512);                            \
  } while (0)

#define PSTAGE(S_, B_)                                                         \
  do {                                                                         \
    const unsigned short* ps_ = Pq + (size_t)(S_)*8192;                        \
    _Pragma("unroll") for (int c_ = 0; c_ < 4; ++c_) {                         \
      const int ch_ = c_ * 4 + wave;                                           \
      gload_lds16(ps_ + ch_ * 512 + lane * 8, &Plds[B_][ch_ * 512]);           \
    }                                                                          \
  } while (0)

  LOADVN(vA, 0);
  LOADVN(vB, 1);
  PSTAGE(0, 0);
  __syncthreads();

  for (int s = 0; s < 32; ++s) {
    const int cb = s & 1;
    if (s < 31) PSTAGE(s + 1, cb ^ 1);
    // --- branch-free MFMA phase (R4 form) ---
#pragma unroll
    for (int i = 0; i < 4; ++i) {
      const int ic = s * 4 + i;
      bf16x8 pb[4];
#pragma unroll
      for (int nt = 0; nt < 4; ++nt)
        pb[nt] = *(const bf16x8*)(&Plds[cb][i * 2048 + nt * 512 + lane * 8]);
      if ((i & 1) == 0) {  // even i -> vA (static alternation)
#pragma unroll
        for (int mt = 0; mt < 2; ++mt)
#pragma unroll
          for (int nt = 0; nt < 4; ++nt)
            o[mt][nt] = __builtin_amdgcn_mfma_f32_16x16x32_bf16(
                vA[mt], pb[nt], o[mt][nt], 0, 0, 0);
        if (ic + 2 < 128) LOADVN(vA, ic + 2);
      } else {
#pragma unroll
        for (int mt = 0; mt < 2; ++mt)
#pragma unroll
          for (int nt = 0; nt < 4; ++nt)
            o[mt][nt] = __builtin_amdgcn_mfma_f32_16x16x32_bf16(
                vB[mt], pb[nt], o[mt][nt], 0, 0, 0);
        if (ic + 2 < 128) LOADVN(vB, ic + 2);
      }
    }
    // --- colsum phase (owned stages only; Plds[cb] valid until barrier) ---
    if ((s >> 3) == dpart) {
#pragma unroll
      for (int i = 0; i < 4; ++i) {
        const int ic = s * 4 + i;
        bf16x8 pb2[4];
#pragma unroll
        for (int nt = 0; nt < 4; ++nt)
          pb2[nt] = *(const bf16x8*)(&Plds[cb][i * 2048 + nt * 512 + lane * 8]);
#pragma unroll
        for (int jo = 0; jo < 2; ++jo) {
          const int j = wave * 2 + jo;
          float c = 0.f;
#pragma unroll
          for (int nt = 0; nt < 4; ++nt)
            c = fmaf(bf16_f32(pb2[nt][j]), rlv[nt], c);
          c += __shfl_xor(c, 1);
          c += __shfl_xor(c, 2);
          c += __shfl_xor(c, 4);
          c += __shfl_xor(c, 8);
          if (l15 == 0) scp[ic * 32 + quad * 8 + j] = c;
        }
      }
    }
    __syncthreads();
  }
#undef LOADVN
#undef PSTAGE

  // epilogue: plain stores, 1/l folded in (per output column q).
  float* ob = out + ((size_t)b * DDIM + dpart * 128 + wave * 32) * NTOK + q0b * 64;
#pragma unroll
  for (int mt = 0; mt < 2; ++mt)
#pragma unroll
    for (int nt = 0; nt < 4; ++nt)
#pragma unroll
      for (int r = 0; r < 4; ++r)
        ob[(size_t)(mt * 16 + quad * 4 + r) * NTOK + nt * 16 + l15] =
            o[mt][nt][r] * rlv[nt];
}

// ---------------------------------------------------------------------------
// K4: scores_out[b][i] = sum_{q0b<64} scpart[b][q0b][i].  4 MB read, tiny.
// ---------------------------------------------------------------------------
__global__ __launch_bounds__(256, 8) void colsum_reduce(
    const float* __restrict__ scpart,
    float* __restrict__ scores_out)
{
  const int b = blockIdx.y;
  const int i = blockIdx.x * 256 + threadIdx.x;
  const float* src = scpart + (size_t)b * 64 * NTOK + i;
  float s = 0.f;
#pragma unroll
  for (int q = 0; q < 64; ++q) s += src[(size_t)q * NTOK];
  scores_out[(size_t)b * NTOK + i] = s;
}

// ---------------------------------------------------------------------------
extern "C" void kernel_launch(void* const* d_in, const int* in_sizes, int n_in,
                              void* d_out, int out_size, void* d_ws, size_t ws_size,
                              hipStream_t stream) {
  const float* x  = (const float*)d_in[0];
  const float* Wk = (const float*)d_in[1];  // dict order: x, Wk, Wq, Wv
  const float* Wq = (const float*)d_in[2];
  const float* Wv = (const float*)d_in[3];

  float* out = (float*)d_out;
  float* scores_out = out + (size_t)NB * DDIM * NTOK;  // tail of d_out

  const size_t mat_elems = (size_t)NB * NTOK * DDIM;   // 8388608
  unsigned short* Qt = (unsigned short*)d_ws;
  unsigned short* Kf = Qt + mat_elems;
  unsigned short* Vt = Kf + mat_elems;
  float* lbuf = (float*)(Vt + mat_elems);              // 64 KB
  unsigned short* Pt = (unsigned short*)(lbuf + (size_t)NB * NTOK);  // 134.2 MB
  float* scpart = (float*)(Pt + (size_t)NB * NTOK * NTOK);           // 4 MB

  // Xb/Wb overlay the head of Pt's region (dead until K2 writes Pt).
  unsigned short* Xb = Pt;                    // 16.8 MB
  unsigned short* Wb = Pt + mat_elems;        // 1.6 MB (3 x 262144)

  hipMemsetAsync(lbuf, 0, (size_t)NB * NTOK * sizeof(float), stream);

  conv_bf16<<<dim3(2432), 256, 0, stream>>>(x, Wq, Wk, Wv, Xb, Wb);

  dim3 g1(NTOK / 64, DDIM / 64, NB);
  qkv_proj<<<g1, 256, 0, stream>>>(Xb, Wb, Qt, Kf, Vt);

  dim3 g2(NTOK / 128, 4, NB);
  attn_lsum_p<<<g2, 256, 0, stream>>>(Qt, Kf, Pt, lbuf);

  attn_pv<<<dim3(1024), 256, 0, stream>>>(Pt, Vt, lbuf, out, scpart);

  colsum_reduce<<<dim3(NTOK / 256, NB), 256, 0, stream>>>(scpart, scores_out);
}

// Round 10
// 332.804 us; speedup vs baseline: 1.4493x; 1.4493x over previous
//
#include <hip/hip_runtime.h>

// B=4, C=512, H=W=64 -> N=4096 tokens, KEY_DIM=VALUE_DIM=512.
// Pipeline (all matmuls on v_mfma_f32_16x16x32_bf16, fp32 accum):
//   K0 conv_bf16  : f32->bf16 AND x transpose: Xb[b][n][c] token-major (LDS
//                   tile bounce).  Wb[m][d][c].  Overlays Pt (dead until K2).
//   K1 qkv_proj   : bf16 GEMM; x staging ONE bf16x8 load/thread/stage.
//   K2 attn_lsum_p: R4/R6 form (256 thr, 2x32KB DMA stages), 92 us.
//   K3 attn_pv    : O = V.Pexp^T + colsum partials (post-loop phase).
//                   R10 FIX of R9's rule-#20 violation: colsum re-partitioned
//                   by ic (wave w owns ic = s*4+w) so every pb2[nt][j] index is
//                   COMPILE-TIME STATIC.  R9's runtime j = wave*2+jo sent pb2
//                   to scratch: WRITE_SIZE 39->466 GB-KB (1.8 KB/thread spill
//                   round-trips), pv 105->241 us.  Same terms, same nt order,
//                   same l15 reduce -> bit-identical scores.
//   K4 colsum_reduce: scores[b][i] = sum_q0b scpart (4MB, tiny).
// Lessons: R5 direct global K-frag loads = 300us (latency death); R1/R2
// atomics cost 31MB RMW + 90MB read-alloc; R7 small blocks doubled barriers;
// R9 runtime-indexed ext_vector -> scratch (rule #20).
// No max-subtraction in softmax: logits ~ N(0,1), exp() can't overflow.
// ws: Qt/Kf/Vt 50.3 MB + l 64 KB + Pexp 134.2 MB (Xb/Wb overlaid) + scpart 4MB.

typedef short bf16x8 __attribute__((ext_vector_type(8)));
typedef float f32x4 __attribute__((ext_vector_type(4)));

#define NTOK 4096
#define DDIM 512
#define NB   4

__device__ __forceinline__ unsigned short f32_bf16(float f) {
  union { float f; unsigned u; } v; v.f = f;
  unsigned r = v.u + 0x7FFFu + ((v.u >> 16) & 1u);  // RNE
  return (unsigned short)(r >> 16);
}

__device__ __forceinline__ float bf16_f32(short s) {
  union { unsigned u; float f; } v;
  v.u = ((unsigned)(unsigned short)s) << 16;
  return v.f;
}

// Async global->LDS DMA, 16B per lane.
__device__ __forceinline__ void gload_lds16(const unsigned short* g,
                                            unsigned short* l) {
  __builtin_amdgcn_global_load_lds(
      (__attribute__((address_space(1))) void*)(g),
      (__attribute__((address_space(3))) void*)(l), 16, 0, 0);
}

// ---------------------------------------------------------------------------
// K0: f32->bf16 + x transpose.  Blocks [0,2048): x [b][c][n] -> Xb [b][n][c]
// via 64x64 LDS tile.  Blocks [2048,2432): Wq/Wk/Wv -> Wb[m][d][c] flat.
// ---------------------------------------------------------------------------
__global__ __launch_bounds__(256, 4) void conv_bf16(
    const float* __restrict__ x,
    const float* __restrict__ Wq,
    const float* __restrict__ Wk,
    const float* __restrict__ Wv,
    unsigned short* __restrict__ Xb,
    unsigned short* __restrict__ Wb)
{
  const int bid = blockIdx.x;
  const int tid = threadIdx.x;
  if (bid < 2048) {
    // x transpose tile: batch b, c-tile ct (8), n-tile nt (64)
    const int b  = bid >> 9;
    const int t  = bid & 511;
    const int c0 = (t >> 6) * 64;
    const int n0 = (t & 63) * 64;
    __shared__ __align__(16) unsigned short T[64][72];  // [n][c]
    const int cr = tid >> 2;        // c row 0..63
    const int cg = tid & 3;         // n group of 16
    const float* src = x + ((size_t)b * DDIM + c0 + cr) * NTOK + n0 + cg * 16;
    float v[16];
#pragma unroll
    for (int e4 = 0; e4 < 4; ++e4) {
      const float4 a = *(const float4*)(src + e4 * 4);
      v[e4 * 4 + 0] = a.x; v[e4 * 4 + 1] = a.y;
      v[e4 * 4 + 2] = a.z; v[e4 * 4 + 3] = a.w;
    }
#pragma unroll
    for (int e = 0; e < 16; ++e) T[cg * 16 + e][cr] = f32_bf16(v[e]);
    __syncthreads();
    const int nr  = tid >> 2;       // n row 0..63
    const int cg2 = tid & 3;        // c group of 16
    unsigned short* dst =
        Xb + ((size_t)b * NTOK + n0 + nr) * DDIM + c0 + cg2 * 16;
    *(bf16x8*)(dst)     = *(const bf16x8*)(&T[nr][cg2 * 16]);
    *(bf16x8*)(dst + 8) = *(const bf16x8*)(&T[nr][cg2 * 16 + 8]);
  } else {
    const int widx = bid - 2048;                 // [0,384)
    const int m    = widx >> 7;                  // 0..2
    const float* wsrc[3] = {Wq, Wk, Wv};
    const float* src = wsrc[m] + (size_t)(widx & 127) * 2048;
    unsigned short* dst = Wb + (size_t)m * 262144 + (size_t)(widx & 127) * 2048;
    const size_t i = (size_t)tid * 8;
    const float4 a = *(const float4*)(src + i);
    const float4 c = *(const float4*)(src + i + 4);
    bf16x8 tv;
    tv[0] = (short)f32_bf16(a.x); tv[1] = (short)f32_bf16(a.y);
    tv[2] = (short)f32_bf16(a.z); tv[3] = (short)f32_bf16(a.w);
    tv[4] = (short)f32_bf16(c.x); tv[5] = (short)f32_bf16(c.y);
    tv[6] = (short)f32_bf16(c.z); tv[7] = (short)f32_bf16(c.w);
    *(bf16x8*)(dst + i) = tv;
  }
}

// ---------------------------------------------------------------------------
// K1: QKV projection (bf16, token-major x).  Q[n,d] = sum_c x[n,c] * Wq[d,c].
// Staging: x and weights each ONE bf16x8 vector load/thread/stage.
// MFMA loop + epilogue identical to original (bit-identical results).
// ---------------------------------------------------------------------------
__global__ __launch_bounds__(256, 4) void qkv_proj(
    const unsigned short* __restrict__ Xb,   // [b][n][c] bf16 token-major
    const unsigned short* __restrict__ Wb,   // [m][d][c] bf16
    unsigned short* __restrict__ Qt,
    unsigned short* __restrict__ Kf,
    unsigned short* __restrict__ Vt)
{
  const int nt0 = blockIdx.x * 64;   // token tile
  const int d0  = blockIdx.y * 64;   // feature tile
  const int b   = blockIdx.z;
  const int tid = threadIdx.x;
  const int wave = tid >> 6;
  const int lane = tid & 63;
  const int l15  = lane & 15;
  const int quad = lane >> 4;

  __shared__ __align__(16) unsigned short Xt[64 * 40];     // [token][c]
  __shared__ __align__(16) unsigned short Wl[3][64 * 40];  // [q/k/v][d][c]

  f32x4 aq[4], ak[4], av[4];
#pragma unroll
  for (int i = 0; i < 4; ++i) {
    aq[i] = (f32x4){0.f,0.f,0.f,0.f};
    ak[i] = (f32x4){0.f,0.f,0.f,0.f};
    av[i] = (f32x4){0.f,0.f,0.f,0.f};
  }

  const unsigned short* xb = Xb + ((size_t)b * NTOK + nt0) * DDIM;
  const int tr  = tid >> 2;   // token row 0..63
  const int cgx = tid & 3;    // c group of 8
  const int wc8 = tid & 3;
  const int wdd = tid >> 2;

  for (int cc = 0; cc < DDIM; cc += 32) {
    __syncthreads();
    *(bf16x8*)(&Xt[tr * 40 + cgx * 8]) =
        *(const bf16x8*)(xb + (size_t)tr * DDIM + cc + cgx * 8);
#pragma unroll
    for (int m = 0; m < 3; ++m) {
      const bf16x8 t = *(const bf16x8*)(
          Wb + (size_t)m * 262144 + (size_t)(d0 + wdd) * 512 + cc + wc8 * 8);
      *(bf16x8*)(&Wl[m][wdd * 40 + wc8 * 8]) = t;
    }
    __syncthreads();

    bf16x8 xa  = *(const bf16x8*)(&Xt[(wave * 16 + l15) * 40 + quad * 8]);
    bf16x8 wva = *(const bf16x8*)(&Wl[2][(wave * 16 + l15) * 40 + quad * 8]);
#pragma unroll
    for (int nt = 0; nt < 4; ++nt) {
      bf16x8 wqf = *(const bf16x8*)(&Wl[0][(nt * 16 + l15) * 40 + quad * 8]);
      bf16x8 wkf = *(const bf16x8*)(&Wl[1][(nt * 16 + l15) * 40 + quad * 8]);
      bf16x8 xbf = *(const bf16x8*)(&Xt[(nt * 16 + l15) * 40 + quad * 8]);
      aq[nt] = __builtin_amdgcn_mfma_f32_16x16x32_bf16(xa,  wqf, aq[nt], 0, 0, 0);
      ak[nt] = __builtin_amdgcn_mfma_f32_16x16x32_bf16(xa,  wkf, ak[nt], 0, 0, 0);
      av[nt] = __builtin_amdgcn_mfma_f32_16x16x32_bf16(wva, xbf, av[nt], 0, 0, 0);
    }
  }

#pragma unroll
  for (int nt = 0; nt < 4; ++nt) {
#pragma unroll
    for (int r = 0; r < 4; ++r) {
      const int tokq = nt0 + wave * 16 + quad * 4 + r;
      const int dq   = d0 + nt * 16 + l15;
      Qt[((size_t)b * NTOK + tokq) * DDIM + dq] = f32_bf16(aq[nt][r]);
      // K fragment-tile store (B-operand of 16x16x32): key=tokq, d=dq
      {
        const int kblk  = (nt0 >> 4) + wave;
        const int dc    = (d0 >> 5) + (nt >> 1);
        const int laneK = ((nt & 1) * 2 + (l15 >> 3)) * 16 + quad * 4 + r;
        Kf[((size_t)(b * 256 + kblk) * 16 + dc) * 512 + laneK * 8 + (l15 & 7)] =
            f32_bf16(ak[nt][r]);
      }
      // V fragment-tile store: d = d0+wave*16+quad*4+r, i = nt0+nt*16+l15
      const int dblk  = (d0 >> 4) + wave;
      const int ic    = (nt0 >> 5) + (nt >> 1);
      const int laneV = ((nt & 1) * 2 + (l15 >> 3)) * 16 + quad * 4 + r;
      Vt[(size_t)b * DDIM * NTOK +
         ((size_t)(dblk * 128 + ic) * 64 + laneV) * 8 + (l15 & 7)] =
          f32_bf16(av[nt][r]);
    }
  }
}

// ---------------------------------------------------------------------------
#define SCALE 0.044194173824159216f  // 1/sqrt(512)

// ---------------------------------------------------------------------------
// K2: QK^T -> Pexp + row-sum atomics.  Grid (32 qb(128q), 4 kp(1024k), NB).
// Wave owns 32 q (qf[2][16] pinned, 128 VGPRs).  32-key stages via
// global_load_lds into Klds[2][32KB]; 2-phase dbuf.  (R4/R6 form, 92 us.)
// ---------------------------------------------------------------------------
__global__ __launch_bounds__(256, 2) void attn_lsum_p(
    const unsigned short* __restrict__ Qt,
    const unsigned short* __restrict__ Kf,
    unsigned short* __restrict__ Pt,
    float* __restrict__ lsum_g)
{
  const int qb = blockIdx.x;   // 128-q block
  const int kp = blockIdx.y;   // 1024-key part
  const int b  = blockIdx.z;
  const int tid  = threadIdx.x;
  const int wave = tid >> 6;
  const int lane = tid & 63;
  const int l15  = lane & 15;
  const int quad = lane >> 4;
  const int q0   = qb * 128 + wave * 32;  // wave's 32 q

  __shared__ __align__(16) unsigned short Klds[2][16384];  // 2 x 32KB

  // Q A-frags pinned: qf[qt][dc], 2x16x4 VGPRs = 128
  bf16x8 qf[2][16];
#pragma unroll
  for (int qt = 0; qt < 2; ++qt) {
    const unsigned short* qp =
        Qt + ((size_t)b * NTOK + q0 + qt * 16 + l15) * DDIM + quad * 8;
#pragma unroll
    for (int dc = 0; dc < 16; ++dc) qf[qt][dc] = *(const bf16x8*)(qp + dc * 32);
  }

  // P region: 64-q granularity
  unsigned short* Pq = Pt + (size_t)b * NTOK * NTOK +
                       (size_t)(qb * 2 + (wave >> 1)) * 262144;
  const int ntb = (wave & 1) * 2;  // nt base within region

  float ls[2][4] = {{0.f,0.f,0.f,0.f},{0.f,0.f,0.f,0.f}};

  // stage kc2 covers key-blocks kp*64 + kc2*2 .. +1 (32 keys, 32KB, flat)
  const unsigned short* Ksrc0 = Kf + ((size_t)(b * 256 + kp * 64) * 16) * 512;

#define KSTAGE(KC_, B_)                                                        \
  do {                                                                         \
    const unsigned short* ks_ = Ksrc0 + (size_t)(KC_)*16384;                   \
    _Pragma("unroll") for (int c_ = 0; c_ < 8; ++c_) {                         \
      const int ch_ = c_ * 4 + wave;                                           \
      gload_lds16(ks_ + ch_ * 512 + lane * 8, &Klds[B_][ch_ * 512]);           \
    }                                                                          \
  } while (0)

  KSTAGE(0, 0);
  __syncthreads();

  for (int kc2 = 0; kc2 < 32; ++kc2) {
    const int cb = kc2 & 1;
    if (kc2 < 31) KSTAGE(kc2 + 1, cb ^ 1);

#pragma unroll
    for (int kt = 0; kt < 2; ++kt) {
      const int kabs = kp * 64 + kc2 * 2 + kt;
      f32x4 s0 = (f32x4){0.f,0.f,0.f,0.f};
      f32x4 s1 = (f32x4){0.f,0.f,0.f,0.f};
#pragma unroll
      for (int dc = 0; dc < 16; ++dc) {
        const bf16x8 kbf =
            *(const bf16x8*)(&Klds[cb][(kt * 16 + dc) * 512 + lane * 8]);
        s0 = __builtin_amdgcn_mfma_f32_16x16x32_bf16(qf[0][dc], kbf, s0, 0, 0, 0);
        s1 = __builtin_amdgcn_mfma_f32_16x16x32_bf16(qf[1][dc], kbf, s1, 0, 0, 0);
      }
      // epilogue: key = kabs*16 + l15, q = q0 + qt*16 + quad*4 + r
      const int ic    = kabs >> 1;
      const int lt_hi = ((kabs & 1) * 2 + (l15 >> 3)) * 16;
      const int jj    = l15 & 7;
#pragma unroll
      for (int r = 0; r < 4; ++r) {
        const float e0 = __expf(s0[r] * SCALE);
        const float e1 = __expf(s1[r] * SCALE);
        ls[0][r] += e0;
        ls[1][r] += e1;
        Pq[((size_t)(ic * 4 + ntb) * 64 + lt_hi + quad * 4 + r) * 8 + jj] =
            f32_bf16(e0);
        Pq[((size_t)(ic * 4 + ntb + 1) * 64 + lt_hi + quad * 4 + r) * 8 + jj] =
            f32_bf16(e1);
      }
    }
    __syncthreads();
  }
#undef KSTAGE

  // reduce over the 16 key-columns (l15) and accumulate l_j
#pragma unroll
  for (int qt = 0; qt < 2; ++qt)
#pragma unroll
    for (int r = 0; r < 4; ++r) {
      float v = ls[qt][r];
      v += __shfl_xor(v, 1);
      v += __shfl_xor(v, 2);
      v += __shfl_xor(v, 4);
      v += __shfl_xor(v, 8);
      if (l15 == 0)
        unsafeAtomicAdd(&lsum_g[(size_t)b * NTOK + q0 + qt * 16 + quad * 4 + r], v);
    }
}

// ---------------------------------------------------------------------------
// K3: O = V.Pexp^T + colsum partials.  1D grid 1024, XCD-swizzled.
// 4 blk/CU x 4 waves = 16 waves/CU.  Wave owns 32 d x 64 q; o[2][4].
// Branch-free MFMA i-loop (R4 form).  Colsum as a post-loop phase on owned
// stages: wave w owns ic = s*4 + w (ONE ic, ALL j=0..7 static -> no runtime
// vector indexing, rule #20).  Same terms/order -> bit-identical scores.
// ---------------------------------------------------------------------------
__global__ __launch_bounds__(256, 4) void attn_pv(
    const unsigned short* __restrict__ Pt,
    const unsigned short* __restrict__ Vt,
    const float* __restrict__ lsum_g,
    float* __restrict__ out,
    float* __restrict__ scpart)
{
  const int g     = blockIdx.x;
  const int xcd   = g & 7;
  const int slot  = g >> 3;                    // [0,128)
  const int combo = (xcd << 1) | (slot >> 6);  // [0,16) = dpart + 4*b
  const int q0b   = slot & 63;
  const int dpart = combo & 3;                 // 0..3, 128 d each
  const int b     = combo >> 2;
  const int tid  = threadIdx.x;
  const int wave = tid >> 6;
  const int lane = tid & 63;
  const int l15  = lane & 15;
  const int quad = lane >> 4;

  const int dblk0 = dpart * 8 + wave * 2;  // base 16-d tile index (2/wave)
  const unsigned short* Pq =
      Pt + (size_t)b * NTOK * NTOK + (size_t)q0b * 262144;  // 128 ic x 2048
  const unsigned short* Vb =
      Vt + (size_t)b * DDIM * NTOK + lane * 8;
  float* scp = scpart + ((size_t)(b * 64 + q0b)) * NTOK;

  __shared__ __align__(16) unsigned short Plds[2][8192];  // 2 x 16KB (4 ic)

  float rlv[4];
#pragma unroll
  for (int nt = 0; nt < 4; ++nt)
    rlv[nt] = 1.0f / lsum_g[(size_t)b * NTOK + q0b * 64 + nt * 16 + l15];

  f32x4 o[2][4];
#pragma unroll
  for (int i = 0; i < 2; ++i)
#pragma unroll
    for (int j = 0; j < 4; ++j) o[i][j] = (f32x4){0.f,0.f,0.f,0.f};

  bf16x8 vA[2], vB[2];

#define LOADVN(D_, IC_)                                                        \
  do {                                                                         \
    _Pragma("unroll") for (int mt = 0; mt < 2; ++mt)                           \
      D_[mt] = *(const bf16x8*)(Vb + (size_t)(dblk0 + mt) * 65536 +            \
                                (size_t)(IC_)*512);                            \
  } while (0)

#define PSTAGE(S_, B_)                                                         \
  do {                                                                         \
    const unsigned short* ps_ = Pq + (size_t)(S_)*8192;                        \
    _Pragma("unroll") for (int c_ = 0; c_ < 4; ++c_) {                         \
      const int ch_ = c_ * 4 + wave;                                           \
      gload_lds16(ps_ + ch_ * 512 + lane * 8, &Plds[B_][ch_ * 512]);           \
    }                                                                          \
  } while (0)

  LOADVN(vA, 0);
  LOADVN(vB, 1);
  PSTAGE(0, 0);
  __syncthreads();

  for (int s = 0; s < 32; ++s) {
    const int cb = s & 1;
    if (s < 31) PSTAGE(s + 1, cb ^ 1);
    // --- branch-free MFMA phase (R4 form) ---
#pragma unroll
    for (int i = 0; i < 4; ++i) {
      const int ic = s * 4 + i;
      bf16x8 pb[4];
#pragma unroll
      for (int nt = 0; nt < 4; ++nt)
        pb[nt] = *(const bf16x8*)(&Plds[cb][i * 2048 + nt * 512 + lane * 8]);
      if ((i & 1) == 0) {  // even i -> vA (static alternation)
#pragma unroll
        for (int mt = 0; mt < 2; ++mt)
#pragma unroll
          for (int nt = 0; nt < 4; ++nt)
            o[mt][nt] = __builtin_amdgcn_mfma_f32_16x16x32_bf16(
                vA[mt], pb[nt], o[mt][nt], 0, 0, 0);
        if (ic + 2 < 128) LOADVN(vA, ic + 2);
      } else {
#pragma unroll
        for (int mt = 0; mt < 2; ++mt)
#pragma unroll
          for (int nt = 0; nt < 4; ++nt)
            o[mt][nt] = __builtin_amdgcn_mfma_f32_16x16x32_bf16(
                vB[mt], pb[nt], o[mt][nt], 0, 0, 0);
        if (ic + 2 < 128) LOADVN(vB, ic + 2);
      }
    }
    // --- colsum phase: wave owns ic = s*4 + wave; all j static (rule #20) ---
    if ((s >> 3) == dpart) {
      const int ic = s * 4 + wave;
      bf16x8 pb2[4];
#pragma unroll
      for (int nt = 0; nt < 4; ++nt)
        pb2[nt] =
            *(const bf16x8*)(&Plds[cb][wave * 2048 + nt * 512 + lane * 8]);
      float cj[8];
#pragma unroll
      for (int j = 0; j < 8; ++j) {
        float c = 0.f;
#pragma unroll
        for (int nt = 0; nt < 4; ++nt)
          c = fmaf(bf16_f32(pb2[nt][j]), rlv[nt], c);
        cj[j] = c;
      }
#pragma unroll
      for (int j = 0; j < 8; ++j) {
        float v_ = cj[j];
        v_ += __shfl_xor(v_, 1);
        v_ += __shfl_xor(v_, 2);
        v_ += __shfl_xor(v_, 4);
        v_ += __shfl_xor(v_, 8);
        cj[j] = v_;
      }
      if (l15 == 0) {
#pragma unroll
        for (int j = 0; j < 8; ++j) scp[ic * 32 + quad * 8 + j] = cj[j];
      }
    }
    __syncthreads();
  }
#undef LOADVN
#undef PSTAGE

  // epilogue: plain stores, 1/l folded in (per output column q).
  float* ob = out + ((size_t)b * DDIM + dpart * 128 + wave * 32) * NTOK + q0b * 64;
#pragma unroll
  for (int mt = 0; mt < 2; ++mt)
#pragma unroll
    for (int nt = 0; nt < 4; ++nt)
#pragma unroll
      for (int r = 0; r < 4; ++r)
        ob[(size_t)(mt * 16 + quad * 4 + r) * NTOK + nt * 16 + l15] =
            o[mt][nt][r] * rlv[nt];
}

// ---------------------------------------------------------------------------
// K4: scores_out[b][i] = sum_{q0b<64} scpart[b][q0b][i].  4 MB read, tiny.
// ---------------------------------------------------------------------------
__global__ __launch_bounds__(256, 8) void colsum_reduce(
    const float* __restrict__ scpart,
    float* __restrict__ scores_out)
{
  const int b = blockIdx.y;
  const int i = blockIdx.x * 256 + threadIdx.x;
  const float* src = scpart + (size_t)b * 64 * NTOK + i;
  float s = 0.f;
#pragma unroll
  for (int q = 0; q < 64; ++q) s += src[(size_t)q * NTOK];
  scores_out[(size_t)b * NTOK + i] = s;
}

// ---------------------------------------------------------------------------
extern "C" void kernel_launch(void* const* d_in, const int* in_sizes, int n_in,
                              void* d_out, int out_size, void* d_ws, size_t ws_size,
                              hipStream_t stream) {
  const float* x  = (const float*)d_in[0];
  const float* Wk = (const float*)d_in[1];  // dict order: x, Wk, Wq, Wv
  const float* Wq = (const float*)d_in[2];
  const float* Wv = (const float*)d_in[3];

  float* out = (float*)d_out;
  float* scores_out = out + (size_t)NB * DDIM * NTOK;  // tail of d_out

  const size_t mat_elems = (size_t)NB * NTOK * DDIM;   // 8388608
  unsigned short* Qt = (unsigned short*)d_ws;
  unsigned short* Kf = Qt + mat_elems;
  unsigned short* Vt = Kf + mat_elems;
  float* lbuf = (float*)(Vt + mat_elems);              // 64 KB
  unsigned short* Pt = (unsigned short*)(lbuf + (size_t)NB * NTOK);  // 134.2 MB
  float* scpart = (float*)(Pt + (size_t)NB * NTOK * NTOK);           // 4 MB

  // Xb/Wb overlay the head of Pt's region (dead until K2 writes Pt).
  unsigned short* Xb = Pt;                    // 16.8 MB
  unsigned short* Wb = Pt + mat_elems;        // 1.6 MB (3 x 262144)

  hipMemsetAsync(lbuf, 0, (size_t)NB * NTOK * sizeof(float), stream);

  conv_bf16<<<dim3(2432), 256, 0, stream>>>(x, Wq, Wk, Wv, Xb, Wb);

  dim3 g1(NTOK / 64, DDIM / 64, NB);
  qkv_proj<<<g1, 256, 0, stream>>>(Xb, Wb, Qt, Kf, Vt);

  dim3 g2(NTOK / 128, 4, NB);
  attn_lsum_p<<<g2, 256, 0, stream>>>(Qt, Kf, Pt, lbuf);

  attn_pv<<<dim3(1024), 256, 0, stream>>>(Pt, Vt, lbuf, out, scpart);

  colsum_reduce<<<dim3(NTOK / 256, NB), 256, 0, stream>>>(scpart, scores_out);
}